// Round 8
// baseline (604.339 us; speedup 1.0000x reference)
//
#include <hip/hip_runtime.h>

// SOMNetwork forward. All four rbf/cdist layers via split-bf16 MFMA GEMM
// (hi/lo decomposition, 3 MFMAs/product).
// L1 (round 8 restructure): channel-serial single GEMM pass writes d^2 (59 MB,
// L3-resident) with a cheap store-only epilogue; std reduce and exp/crelu/pool
// become separate BW-bound coalesced kernels. Kills the duplicated
// extraction+GEMM and the shuffle/psm-heavy epilogues of rounds 6-7.
// L2/L3/L4: 256x256-tile 8-wave GEMM, dist buffers hold squared distances,
// channels batched into grid z.

typedef unsigned short u16;
typedef short bf16x8 __attribute__((ext_vector_type(8)));
typedef float f32x4 __attribute__((ext_vector_type(4)));

#define STRIPES 64
#define ACC_L2 0            // 64 stripes * 2 doubles per layer region
#define ACC_L3 128
#define ACC_L4 256
#define ACC_TOTAL 384

__device__ __forceinline__ u16 f2bf(float f) {
  unsigned int u = __float_as_uint(f);
  unsigned int r = (u + 0x7fffu + ((u >> 16) & 1u)) >> 16;
  return (u16)r;
}
__device__ __forceinline__ float bf2f(u16 h) {
  return __uint_as_float(((unsigned int)h) << 16);
}
__device__ __forceinline__ float fexp(float x) { return __expf(x); }
__device__ __forceinline__ float fsqrt(float x) { return __builtin_amdgcn_sqrtf(x); }
__device__ __forceinline__ void gload16(const void* g, const void* l) {
  __builtin_amdgcn_global_load_lds(
      (const __attribute__((address_space(1))) unsigned int*)g,
      (__attribute__((address_space(3))) unsigned int*)l, 16, 0, 0);
}

__global__ void zero_acc_kernel(double* __restrict__ acc, int n) {
  int i = blockIdx.x * blockDim.x + threadIdx.x;
  if (i < n) acc[i] = 0.0;
}

// ---------------- weight prep: fp32 -> hi/lo bf16 (padded) + row norms ----------------
__global__ __launch_bounds__(128) void w_prep(
    const float* __restrict__ W, int O, int K, int Opad, int Kp,
    u16* __restrict__ hi, u16* __restrict__ lo, float* __restrict__ wn)
{
  __shared__ float red[2];
  int o = blockIdx.x, cc = blockIdx.y, t = threadIdx.x;
  const float* src = W + ((size_t)cc * O + o) * K;
  u16* dh = hi + ((size_t)cc * Opad + o) * Kp;
  u16* dl = lo + ((size_t)cc * Opad + o) * Kp;
  float p = 0.f;
  for (int k = t; k < Kp; k += 128) {
    float v = (o < O && k < K) ? src[k] : 0.f;
    u16 h = f2bf(v);
    u16 l = f2bf(v - bf2f(h));
    dh[k] = h; dl[k] = l;
    p = fmaf(v, v, p);
  }
  for (int off = 32; off; off >>= 1) p += __shfl_down(p, off, 64);
  if ((t & 63) == 0) red[t >> 6] = p;
  __syncthreads();
  if (t == 0) wn[(size_t)cc * Opad + o] = red[0] + red[1];
}

// ---------------- L1 GEMM pass: fused patch extraction + MFMA + d^2 store ----------------
// One block = 2 images (128 rows: im*64 + pos, pos 0..35 valid), O=128 (100 valid), K=32.
__global__ __launch_bounds__(256) void l1_gemm_d2(
    const float* __restrict__ x, int c,
    const u16* __restrict__ Wh, const u16* __restrict__ Wl,
    const float* __restrict__ wn, float* __restrict__ dist1)
{
  __shared__ __align__(16) u16 sm[16384];
  __shared__ float img[1568];
  __shared__ float pnsm[512];
  __shared__ float pnloc[128];
  const int t = threadIdx.x;
  const int w = t >> 6, lane = t & 63;
  const int b0 = blockIdx.x * 2;

  // B staging (async)
  {
    const int kk = (w & 3) * 8;
#pragma unroll
    for (int u = 0; u < 2; ++u) {
      const size_t gb = (size_t)(u * 64 + lane) * 32 + kk;
      const int ls = ((w & 3) * 128 + u * 64) * 8;
      gload16(Wh + gb, sm + 8192 + ls);
      gload16(Wl + gb, sm + 12288 + ls);
    }
  }
  // raw images -> LDS
#pragma unroll
  for (int im = 0; im < 2; ++im) {
    if (t < 196)
      ((float4*)(img + im * 784))[t] =
          ((const float4*)(x + ((size_t)(b0 + im) * 3 + c) * 784))[t];
  }
  __syncthreads();
  // extraction: 512 A-slots, hi/lo conversion + pnorm partials
  for (int s = t; s < 512; s += 256) {
    int q = s >> 7, row = s & 127;
    int im = row >> 6, pr = row & 63;
    int pi = pr / 6, pj = pr - pi * 6;
    const float* ib = img + im * 784 + pi * 4 * 28 + pj * 4;
    float v[8]; float pn = 0.f;
#pragma unroll
    for (int e = 0; e < 8; ++e) {
      int k = q * 8 + e;
      float val = 0.f;
      if (pr < 36 && k < 25) { int r = k / 5, ss = k - r * 5; val = ib[r * 28 + ss]; }
      v[e] = val; pn = fmaf(val, val, pn);
    }
    u16 hi8[8], lo8[8];
#pragma unroll
    for (int e = 0; e < 8; ++e) {
      u16 h = f2bf(v[e]); hi8[e] = h; lo8[e] = f2bf(v[e] - bf2f(h));
    }
    *(bf16x8*)(sm + (q * 128 + row) * 8) = *(bf16x8*)hi8;
    *(bf16x8*)(sm + 4096 + (q * 128 + row) * 8) = *(bf16x8*)lo8;
    pnsm[s] = pn;
  }
  asm volatile("s_waitcnt vmcnt(0)" ::: "memory");
  __syncthreads();
  if (t < 128) pnloc[t] = pnsm[t] + pnsm[128 + t] + pnsm[256 + t] + pnsm[384 + t];

  const int wr = w >> 1, wc = w & 1;
  const int q4 = lane >> 4, r16 = lane & 15;
  f32x4 accv[4][4];
#pragma unroll
  for (int i = 0; i < 4; ++i)
#pragma unroll
    for (int j = 0; j < 4; ++j) accv[i][j] = (f32x4){0.f, 0.f, 0.f, 0.f};

  bf16x8 Ah[4], Al[4], Bh[4], Bl[4];
#pragma unroll
  for (int i = 0; i < 4; ++i) {
    int ao = (q4 * 128 + wr * 64 + i * 16 + r16) * 8;
    int bo = (q4 * 128 + wc * 64 + i * 16 + r16) * 8;
    Ah[i] = *(const bf16x8*)(sm + ao);
    Al[i] = *(const bf16x8*)(sm + 4096 + ao);
    Bh[i] = *(const bf16x8*)(sm + 8192 + bo);
    Bl[i] = *(const bf16x8*)(sm + 12288 + bo);
  }
#pragma unroll
  for (int i = 0; i < 4; ++i)
#pragma unroll
    for (int j = 0; j < 4; ++j) {
      accv[i][j] = __builtin_amdgcn_mfma_f32_16x16x32_bf16(Ah[i], Bh[j], accv[i][j], 0, 0, 0);
      accv[i][j] = __builtin_amdgcn_mfma_f32_16x16x32_bf16(Al[i], Bh[j], accv[i][j], 0, 0, 0);
      accv[i][j] = __builtin_amdgcn_mfma_f32_16x16x32_bf16(Ah[i], Bl[j], accv[i][j], 0, 0, 0);
    }
  __syncthreads();   // pnloc visible

  // epilogue: plain d^2 stores, no reductions
  int colv[4]; float wnv[4];
#pragma unroll
  for (int j = 0; j < 4; ++j) {
    colv[j] = wc * 64 + j * 16 + r16;
    wnv[j] = (colv[j] < 100) ? wn[colv[j]] : 0.f;
  }
#pragma unroll
  for (int i = 0; i < 4; ++i) {
#pragma unroll
    for (int r = 0; r < 4; ++r) {
      int pos = i * 16 + q4 * 4 + r;
      if (pos < 36) {
        float pn = pnloc[wr * 64 + pos];
        float* drow = dist1 + ((size_t)(b0 + wr) * 36 + pos) * 100;
#pragma unroll
        for (int j = 0; j < 4; ++j) {
          if (colv[j] < 100) {
            float d2 = pn + wnv[j] - 2.f * accv[i][j][r];
            drow[colv[j]] = fmaxf(d2, 0.f) + 1e-12f;
          }
        }
      }
    }
  }
}

// ---------------- L1 std reduce: d^2 -> per-(pos,stripe) s/q partials ----------------
__global__ __launch_bounds__(256) void l1_reduce_bw(
    const float* __restrict__ d1, int B, float* __restrict__ part)
{
  __shared__ float sh[8];
  int pos = blockIdx.x, stripe = blockIdx.y, t = threadIdx.x;
  int ch = t & 127, bsub = t >> 7;
  float s = 0.f, q = 0.f;
  if (ch < 100) {
    int nb = B / 64;
    for (int bi = bsub; bi < nb; bi += 2) {
      float v = d1[((size_t)(bi * 64 + stripe) * 36 + pos) * 100 + ch];
      s += fsqrt(v); q += v;
    }
  }
  for (int off = 32; off; off >>= 1) {
    s += __shfl_down(s, off, 64);
    q += __shfl_down(q, off, 64);
  }
  if ((t & 63) == 0) { sh[(t >> 6) * 2] = s; sh[(t >> 6) * 2 + 1] = q; }
  __syncthreads();
  if (t == 0) {
    s = sh[0] + sh[2] + sh[4] + sh[6];
    q = sh[1] + sh[3] + sh[5] + sh[7];
    part[pos * STRIPES + stripe] = s;
    part[(36 + pos) * STRIPES + stripe] = q;
  }
}

__global__ __launch_bounds__(256) void l1_part_fin(
    const float* __restrict__ part, int NB, float* __restrict__ inv36, double n)
{
  __shared__ double sh[8];
  int pos = blockIdx.x, t = threadIdx.x;
  double s = 0.0, q = 0.0;
  for (int b = t; b < NB; b += 256) {
    s += part[(size_t)pos * NB + b];
    q += part[(size_t)(36 + pos) * NB + b];
  }
  for (int off = 32; off; off >>= 1) {
    s += __shfl_down(s, off, 64);
    q += __shfl_down(q, off, 64);
  }
  if ((t & 63) == 0) { sh[(t >> 6) * 2] = s; sh[(t >> 6) * 2 + 1] = q; }
  __syncthreads();
  if (t == 0) {
    s = sh[0] + sh[2] + sh[4] + sh[6];
    q = sh[1] + sh[3] + sh[5] + sh[7];
    double var = (q - s * s / n) / (n - 1.0);
    inv36[pos] = var > 0.0 ? (float)(0.5 / var) : __builtin_inff();
  }
}

// ---------------- L1 sfm: d^2 -> exp/crelu -> 2x2 alpha-pool -> X hi/lo + xn ----------------
__global__ __launch_bounds__(128) void l1_sfm_lite(
    const float* __restrict__ d1, const float* __restrict__ inv36,
    const float* __restrict__ cb,
    u16* __restrict__ Xhi, u16* __restrict__ Xlo, float* __restrict__ xn)
{
  __shared__ float inv_s[36];
  __shared__ float xnsm[9][2];
  int b = blockIdx.x, t = threadIdx.x;
  if (t < 36) inv_s[t] = inv36[t];
  __syncthreads();
  const float* db = d1 + (size_t)b * 3600;
  float bias = cb[0];
  int wv = t >> 6;
#pragma unroll
  for (int IJ = 0; IJ < 9; ++IJ) {
    const int I = IJ / 3, J = IJ - I * 3;
    const int p00 = 12 * I + 2 * J;
    float v = 0.f;
    if (t < 100) {
      float e00 = fexp(-db[p00 * 100 + t] * inv_s[p00]);
      float e01 = fexp(-db[(p00 + 1) * 100 + t] * inv_s[p00 + 1]);
      float e10 = fexp(-db[(p00 + 6) * 100 + t] * inv_s[p00 + 6]);
      float e11 = fexp(-db[(p00 + 7) * 100 + t] * inv_s[p00 + 7]);
      e00 = (e00 >= bias) ? e00 : 0.f;
      e01 = (e01 >= bias) ? e01 : 0.f;
      e10 = (e10 >= bias) ? e10 : 0.f;
      e11 = (e11 >= bias) ? e11 : 0.f;
      v = 0.25f * (fmaf(0.729f, e00, 0.81f * e01) + fmaf(0.9f, e10, e11));
    }
    size_t xrow = (size_t)b * 9 + IJ;
    u16 h = f2bf(v);
    u16 l = f2bf(v - bf2f(h));
    Xhi[xrow * 128 + t] = h;
    Xlo[xrow * 128 + t] = l;
    float p = v * v;
    for (int off = 32; off; off >>= 1) p += __shfl_down(p, off, 64);
    if ((t & 63) == 0) xnsm[IJ][wv] = p;
  }
  __syncthreads();
  if (t < 9) xn[(size_t)b * 9 + t] = xnsm[t][0] + xnsm[t][1];
}

// ---------------- 256x256-tile 8-wave split-bf16 MFMA cdist GEMM ----------------
__global__ __launch_bounds__(512, 2) void gemm_dist_mfma2(
    const u16* __restrict__ Xhi, const u16* __restrict__ Xlo,
    const u16* __restrict__ Whi, const u16* __restrict__ Wlo,
    const float* __restrict__ xn, const float* __restrict__ wn,
    float* __restrict__ dist, int O, int Kp,
    double* __restrict__ acc, int accbase, int c0,
    int sXc, int sWc, int sxnc, int swnc, int sdistc)
{
  __shared__ __align__(16) u16 sm[32768];
  int zi = blockIdx.z, c = c0 + zi;
  Xhi += (size_t)zi * sXc; Xlo += (size_t)zi * sXc;
  Whi += (size_t)c * sWc;  Wlo += (size_t)c * sWc;
  xn += (size_t)zi * sxnc; wn += (size_t)c * swnc;
  dist += (size_t)zi * sdistc;
  acc += (size_t)c * ACC_TOTAL;

  const int t = threadIdx.x;
  const int w = t >> 6, lane = t & 63;
  const int wr = w >> 1, wc = w & 1;
  const int sq = w & 3, half = w >> 2;
  const int m0 = blockIdx.x * 256, o0 = blockIdx.y * 256;
  const int q4 = lane >> 4, r16 = lane & 15;

  f32x4 accv[4][8];
#pragma unroll
  for (int i = 0; i < 4; ++i)
#pragma unroll
    for (int j = 0; j < 8; ++j) accv[i][j] = (f32x4){0.f, 0.f, 0.f, 0.f};

  for (int k0 = 0; k0 < Kp; k0 += 32) {
    const int kk = k0 + sq * 8;
#pragma unroll
    for (int u = 0; u < 2; ++u) {
      const int row = half * 128 + u * 64 + lane;
      const size_t ga = (size_t)(m0 + row) * Kp + kk;
      const size_t gb = (size_t)(o0 + row) * Kp + kk;
      const int ls = (sq * 256 + half * 128 + u * 64) * 8;
      gload16(Xhi + ga, sm + ls);
      gload16(Xlo + ga, sm + 8192 + ls);
      gload16(Whi + gb, sm + 16384 + ls);
      gload16(Wlo + gb, sm + 24576 + ls);
    }
    asm volatile("s_waitcnt vmcnt(0)" ::: "memory");
    __syncthreads();

    bf16x8 Ah[4], Al[4];
#pragma unroll
    for (int i = 0; i < 4; ++i) {
      int ao = (q4 * 256 + wr * 64 + i * 16 + r16) * 8;
      Ah[i] = *(const bf16x8*)(sm + ao);
      Al[i] = *(const bf16x8*)(sm + 8192 + ao);
    }
#pragma unroll
    for (int j = 0; j < 8; ++j) {
      int bo = (q4 * 256 + wc * 128 + j * 16 + r16) * 8;
      bf16x8 Bh = *(const bf16x8*)(sm + 16384 + bo);
      bf16x8 Bl = *(const bf16x8*)(sm + 24576 + bo);
#pragma unroll
      for (int i = 0; i < 4; ++i) {
        accv[i][j] = __builtin_amdgcn_mfma_f32_16x16x32_bf16(Ah[i], Bh, accv[i][j], 0, 0, 0);
        accv[i][j] = __builtin_amdgcn_mfma_f32_16x16x32_bf16(Al[i], Bh, accv[i][j], 0, 0, 0);
        accv[i][j] = __builtin_amdgcn_mfma_f32_16x16x32_bf16(Ah[i], Bl, accv[i][j], 0, 0, 0);
      }
    }
    __syncthreads();
  }

  double s = 0.0, qd = 0.0;
#pragma unroll
  for (int i = 0; i < 4; ++i) {
    const int mb = m0 + wr * 64 + i * 16 + q4 * 4;
    float xnv[4];
#pragma unroll
    for (int r = 0; r < 4; ++r) xnv[r] = xn[mb + r];
    float sf = 0.f, qf = 0.f;
#pragma unroll
    for (int j = 0; j < 8; ++j) {
      const int o = o0 + wc * 128 + j * 16 + r16;
      if (o < O) {
        const float wnv = wn[o];
#pragma unroll
        for (int r = 0; r < 4; ++r) {
          float d2 = xnv[r] + wnv - 2.f * accv[i][j][r];
          float d2c = fmaxf(d2, 0.f) + 1e-12f;
          dist[(size_t)(mb + r) * O + o] = d2c;
          sf += fsqrt(d2c); qf += d2c;
        }
      }
    }
    s += sf; qd += qf;
  }
  for (int off = 32; off; off >>= 1) {
    s += __shfl_down(s, off, 64);
    qd += __shfl_down(qd, off, 64);
  }
  double* redsm = (double*)sm;
  if (lane == 0) { redsm[w * 2] = s; redsm[w * 2 + 1] = qd; }
  __syncthreads();
  if (t == 0) {
    s = 0.0; qd = 0.0;
#pragma unroll
    for (int ww = 0; ww < 8; ++ww) { s += redsm[ww * 2]; qd += redsm[ww * 2 + 1]; }
    int stripe = (blockIdx.x + blockIdx.y * gridDim.x) & (STRIPES - 1);
    atomicAdd(&acc[accbase + stripe * 2], s);
    atomicAdd(&acc[accbase + stripe * 2 + 1], qd);
  }
}

__device__ __forceinline__ float block_inv_from_acc(
    const double* __restrict__ acc, int base, double n, float* sh)
{
  __syncthreads();
  int t = threadIdx.x;
  if (t < 64) {
    double s = acc[base + 2 * t], q = acc[base + 2 * t + 1];
    for (int off = 32; off; off >>= 1) {
      s += __shfl_down(s, off, 64);
      q += __shfl_down(q, off, 64);
    }
    if (t == 0) {
      double var = (q - s * s / n) / (n - 1.0);
      *sh = var > 0.0 ? (float)(0.5 / var) : __builtin_inff();
    }
  }
  __syncthreads();
  return *sh;
}

// exp -> crelu(cb1) -> [0.81,0.9,1]/3 pool -> hi/lo (Kp=256) + xn   (dist2 = d^2)
__global__ __launch_bounds__(256) void l2_sfm(
    const float* __restrict__ dist2, const double* __restrict__ acc, double n,
    const float* __restrict__ cb, u16* __restrict__ Xhi, u16* __restrict__ Xlo,
    float* __restrict__ xn, int c0, int sdistc, int sXc, int sxnc)
{
  __shared__ float shinv;
  __shared__ float red[4];
  int zi = blockIdx.z, c = c0 + zi;
  dist2 += (size_t)zi * sdistc;
  Xhi += (size_t)zi * sXc; Xlo += (size_t)zi * sXc; xn += (size_t)zi * sxnc;
  float inv = block_inv_from_acc(acc + (size_t)c * ACC_TOTAL, ACC_L2, n, &shinv);
  int b = blockIdx.x, u = blockIdx.y, ch = threadIdx.x;
  float bias = cb[1];
  float v = 0.f;
  if (ch < 225) {
    const float av[3] = {0.81f, 0.9f, 1.0f};
    float a = 0.f;
#pragma unroll
    for (int vv = 0; vv < 3; ++vv) {
      float d2 = dist2[((size_t)b * 9 + u * 3 + vv) * 225 + ch];
      float e = fexp(-d2 * inv);
      e = (e >= bias) ? e : 0.f;
      a = fmaf(e, av[vv], a);
    }
    v = a * (1.f / 3.f);
  }
  size_t row = (size_t)b * 3 + u;
  u16 h = f2bf(v);
  u16 l = f2bf(v - bf2f(h));
  Xhi[row * 256 + ch] = h;
  Xlo[row * 256 + ch] = l;
  float p = v * v;
  for (int off = 32; off; off >>= 1) p += __shfl_down(p, off, 64);
  if ((ch & 63) == 0) red[ch >> 6] = p;
  __syncthreads();
  if (ch == 0) xn[row] = red[0] + red[1] + red[2] + red[3];
}

// exp -> crelu(cb2) -> [0.81,0.9,1]/3 pool -> hi/lo (Kp=640) + xn   (dist3 = d^2)
__global__ __launch_bounds__(256) void l3_sfm(
    const float* __restrict__ dist3, const double* __restrict__ acc, double n,
    const float* __restrict__ cb, u16* __restrict__ Xhi, u16* __restrict__ Xlo,
    float* __restrict__ xn, int c0, int sdistc, int sXc, int sxnc)
{
  __shared__ float shinv;
  __shared__ float red[4];
  int zi = blockIdx.y, c = c0 + zi;
  dist3 += (size_t)zi * sdistc;
  Xhi += (size_t)zi * sXc; Xlo += (size_t)zi * sXc; xn += (size_t)zi * sxnc;
  float inv = block_inv_from_acc(acc + (size_t)c * ACC_TOTAL, ACC_L3, n, &shinv);
  int b = blockIdx.x, t = threadIdx.x;
  float bias = cb[2];
  const float au[3] = {0.81f, 0.9f, 1.0f};
  float p = 0.f;
  for (int ch = t; ch < 640; ch += 256) {
    float v = 0.f;
    if (ch < 625) {
      float a = 0.f;
#pragma unroll
      for (int u = 0; u < 3; ++u) {
        float d2 = dist3[((size_t)b * 3 + u) * 625 + ch];
        float e = fexp(-d2 * inv);
        e = (e >= bias) ? e : 0.f;
        a = fmaf(e, au[u], a);
      }
      v = a * (1.f / 3.f);
    }
    u16 h = f2bf(v);
    u16 l = f2bf(v - bf2f(h));
    Xhi[(size_t)b * 640 + ch] = h;
    Xlo[(size_t)b * 640 + ch] = l;
    p = fmaf(v, v, p);
  }
  for (int off = 32; off; off >>= 1) p += __shfl_down(p, off, 64);
  if ((t & 63) == 0) red[t >> 6] = p;
  __syncthreads();
  if (t == 0) xn[b] = red[0] + red[1] + red[2] + red[3];
}

// L4 exp/crelu fused into FC; loops nc channels internally  (dist4 = d^2)
__global__ __launch_bounds__(128) void fc_acc(
    const float* __restrict__ dist4, const double* __restrict__ acc, double n,
    const float* __restrict__ cb, const float* __restrict__ fcw,
    const float* __restrict__ fcb, float* __restrict__ out,
    int c0, int nc, int sdistc)
{
  __shared__ float shinv;
  int b = blockIdx.x, t = threadIdx.x;
  float bias = cb[3];
  float p[10];
#pragma unroll
  for (int k = 0; k < 10; ++k) p[k] = 0.f;
  for (int zi = 0; zi < nc; ++zi) {
    int c = c0 + zi;
    float inv = block_inv_from_acc(acc + (size_t)c * ACC_TOTAL, ACC_L4, n, &shinv);
    const float* d4 = dist4 + (size_t)zi * sdistc;
    for (int j = t; j < 1225; j += 128) {
      float d2 = d4[(size_t)b * 1225 + j];
      float v = fexp(-d2 * inv);
      v = (v >= bias) ? v : 0.f;
#pragma unroll
      for (int k = 0; k < 10; ++k) p[k] = fmaf(v, fcw[k * 3675 + c * 1225 + j], p[k]);
    }
  }
#pragma unroll
  for (int k = 0; k < 10; ++k)
    for (int off = 32; off; off >>= 1) p[k] += __shfl_down(p[k], off, 64);
  __shared__ float red[2][10];
  int wave = t >> 6;
  if ((t & 63) == 0) {
#pragma unroll
    for (int k = 0; k < 10; ++k) red[wave][k] = p[k];
  }
  __syncthreads();
  if (t < 10) {
    float v = red[0][t] + red[1][t];
    if (c0 == 0) out[(size_t)b * 10 + t] = fcb[t] + v;
    else         out[(size_t)b * 10 + t] += v;
  }
}

extern "C" void kernel_launch(void* const* d_in, const int* in_sizes, int n_in,
                              void* d_out, int out_size, void* d_ws, size_t ws_size,
                              hipStream_t stream) {
  const float* x   = (const float*)d_in[0];
  const float* w1  = (const float*)d_in[1];
  const float* w2  = (const float*)d_in[2];
  const float* w3  = (const float*)d_in[3];
  const float* w4  = (const float*)d_in[4];
  const float* fcw = (const float*)d_in[5];
  const float* fcb = (const float*)d_in[6];
  const float* cb  = (const float*)d_in[7];
  float* out = (float*)d_out;
  const int B = in_sizes[0] / (3 * 28 * 28);   // 4096
  const int M2 = B * 9, M3 = B * 3;
  const int NB = B / 2;

  const size_t W2SZ = 256 * 128, W3SZ = 768 * 256, W4SZ = (size_t)1280 * 640;
  const size_t WTOT = 3 * (W2SZ + W3SZ + W4SZ);

  bool batched = true;
  u16 *Xbase, *Whi, *Wlo, *W1h, *W1l;
  float *wn, *w1n, *xn, *inv36, *part;
  double* accd;
  float* Sf;
  for (int attempt = 0; attempt < 2; ++attempt) {
    size_t cur = 0;
    char* basep = (char*)d_ws;
    auto take = [&](size_t bytes) {
      void* r = basep + cur;
      cur = (cur + bytes + 255) & ~(size_t)255;
      return r;
    };
    int nc = batched ? 3 : 1;
    size_t Ssz = (size_t)M2 * 225 * 4 * nc;          // dist2 (largest batched)
    size_t d1sz = (size_t)B * 3600 * 4;              // L1 d^2 (single channel)
    if (d1sz > Ssz) Ssz = d1sz;
    Sf = (float*)take(Ssz);
    Xbase = (u16*)take((size_t)M2 * 128 * 2 * 2 * nc);
    Whi = (u16*)take(WTOT * 2); Wlo = (u16*)take(WTOT * 2);
    W1h = (u16*)take(12288 * 2); W1l = (u16*)take(12288 * 2);
    wn  = (float*)take(3 * (256 + 768 + 1280) * 4);
    w1n = (float*)take(384 * 4);
    xn    = (float*)take((size_t)M2 * 4 * nc);
    inv36 = (float*)take(40 * 4);
    part  = (float*)take(72 * STRIPES * 4);
    accd  = (double*)take(3 * ACC_TOTAL * 8);
    if (cur <= ws_size) break;
    batched = false;
  }
  const int nc = batched ? 3 : 1;

  const int sX2c   = batched ? M2 * 128 * 2 : 0;
  const int sX3c   = batched ? M3 * 256 * 2 : 0;
  const int sX4c   = batched ? B * 640 * 2 : 0;
  const int sD2c   = batched ? M2 * 225 : 0;
  const int sD3c   = batched ? M3 * 625 : 0;
  const int sD4c   = batched ? B * 1225 : 0;
  const int sXn2c  = batched ? M2 : 0;
  const int sXn3c  = batched ? M3 : 0;
  const int sXn4c  = batched ? B : 0;

  u16* x2hi = Xbase;   u16* x2lo = Xbase + (size_t)M2 * 128;
  u16* x3hi = Xbase;   u16* x3lo = Xbase + (size_t)M3 * 256;
  u16* x4hi = Xbase;   u16* x4lo = Xbase + (size_t)B * 640;
  u16* Whi2 = Whi;                 u16* Wlo2 = Wlo;                 float* wn2 = wn;
  u16* Whi3 = Whi + 3 * W2SZ;      u16* Wlo3 = Wlo + 3 * W2SZ;      float* wn3 = wn + 3 * 256;
  u16* Whi4 = Whi + 3 * (W2SZ + W3SZ); u16* Wlo4 = Wlo + 3 * (W2SZ + W3SZ);
  float* wn4 = wn + 3 * (256 + 768);

  zero_acc_kernel<<<(3 * ACC_TOTAL + 255) / 256, 256, 0, stream>>>(accd, 3 * ACC_TOTAL);
  w_prep<<<dim3(128, 3),  128, 0, stream>>>(w1, 100, 25,  128, 32,  W1h,  W1l,  w1n);
  w_prep<<<dim3(256, 3),  128, 0, stream>>>(w2, 225, 100, 256, 128, Whi2, Wlo2, wn2);
  w_prep<<<dim3(768, 3),  128, 0, stream>>>(w3, 625, 225, 768, 256, Whi3, Wlo3, wn3);
  w_prep<<<dim3(1280, 3), 128, 0, stream>>>(w4, 1225, 625, 1280, 640, Whi4, Wlo4, wn4);

  for (int c0 = 0; c0 < 3; c0 += nc) {
    // ---- L1: channel-serial (d^2 buffer Sf reused per channel) ----
    for (int ci = 0; ci < nc; ++ci) {
      int c = c0 + ci;
      l1_gemm_d2<<<NB, 256, 0, stream>>>(
          x, c, W1h + (size_t)c * 4096, W1l + (size_t)c * 4096, w1n + (size_t)c * 128, Sf);
      l1_reduce_bw<<<dim3(36, STRIPES), 256, 0, stream>>>(Sf, B, part);
      l1_part_fin<<<36, 256, 0, stream>>>(part, STRIPES, inv36, (double)B * 100.0);
      l1_sfm_lite<<<B, 128, 0, stream>>>(
          Sf, inv36, cb, x2hi + (size_t)ci * sX2c, x2lo + (size_t)ci * sX2c,
          xn + (size_t)ci * sXn2c);
    }

    // L2: (M2 x 128) x (256 x 128) -> dist2 (M2 x 225)
    gemm_dist_mfma2<<<dim3(M2 / 256, 1, nc), 512, 0, stream>>>(
        x2hi, x2lo, Whi2, Wlo2, xn, wn2, Sf, 225, 128, accd, ACC_L2, c0,
        sX2c, (int)W2SZ, sXn2c, 256, sD2c);
    l2_sfm<<<dim3(B, 3, nc), 256, 0, stream>>>(
        Sf, accd, (double)M2 * 225.0, cb, x3hi, x3lo, xn, c0, sD2c, sX3c, sXn3c);

    // L3: (M3 x 256) x (768 x 256) -> dist3 (M3 x 625)
    gemm_dist_mfma2<<<dim3(M3 / 256, 3, nc), 512, 0, stream>>>(
        x3hi, x3lo, Whi3, Wlo3, xn, wn3, Sf, 625, 256, accd, ACC_L3, c0,
        sX3c, (int)W3SZ, sXn3c, 768, sD3c);
    l3_sfm<<<dim3(B, nc), 256, 0, stream>>>(
        Sf, accd, (double)M3 * 625.0, cb, x4hi, x4lo, xn, c0, sD3c, sX4c, sXn4c);

    // L4: (B x 640) x (1280 x 640) -> dist4 (B x 1225)
    gemm_dist_mfma2<<<dim3(B / 256, 5, nc), 512, 0, stream>>>(
        x4hi, x4lo, Whi4, Wlo4, xn, wn4, Sf, 1225, 640, accd, ACC_L4, c0,
        sX4c, (int)W4SZ, sXn4c, 1280, sD4c);
    fc_acc<<<B, 128, 0, stream>>>(
        Sf, accd, (double)B * 1225.0, cb, fcw, fcb, out, c0, nc, sD4c);
  }
}

// Round 9
// 564.061 us; speedup vs baseline: 1.0714x; 1.0714x over previous
//
#include <hip/hip_runtime.h>

// SOMNetwork forward. All four rbf/cdist layers via split-bf16 MFMA GEMM
// (hi/lo decomposition, 3 MFMAs/product).
// L1: channel-serial single GEMM pass writes d^2 (L3-resident) + BW-bound
// std-reduce and sfm kernels.
// L2/L3/L4 (round 9): 256x256-tile 8-wave GEMM with SOFTWARE-PIPELINED
// double-buffered LDS staging using raw s_barrier (compiler __syncthreads
// force-drains vmcnt(0), serializing stage->compute; raw barriers let the
// prefetch stay in flight across the barrier). 128 KB LDS, 1 block/CU.
// Channels batched into grid z.

typedef unsigned short u16;
typedef short bf16x8 __attribute__((ext_vector_type(8)));
typedef float f32x4 __attribute__((ext_vector_type(4)));

#define STRIPES 64
#define ACC_L2 0            // 64 stripes * 2 doubles per layer region
#define ACC_L3 128
#define ACC_L4 256
#define ACC_TOTAL 384

__device__ __forceinline__ u16 f2bf(float f) {
  unsigned int u = __float_as_uint(f);
  unsigned int r = (u + 0x7fffu + ((u >> 16) & 1u)) >> 16;
  return (u16)r;
}
__device__ __forceinline__ float bf2f(u16 h) {
  return __uint_as_float(((unsigned int)h) << 16);
}
__device__ __forceinline__ float fexp(float x) { return __expf(x); }
__device__ __forceinline__ float fsqrt(float x) { return __builtin_amdgcn_sqrtf(x); }
__device__ __forceinline__ void gload16(const void* g, const void* l) {
  __builtin_amdgcn_global_load_lds(
      (const __attribute__((address_space(1))) unsigned int*)g,
      (__attribute__((address_space(3))) unsigned int*)l, 16, 0, 0);
}

__global__ void zero_acc_kernel(double* __restrict__ acc, int n) {
  int i = blockIdx.x * blockDim.x + threadIdx.x;
  if (i < n) acc[i] = 0.0;
}

// ---------------- weight prep: fp32 -> hi/lo bf16 (padded) + row norms ----------------
__global__ __launch_bounds__(128) void w_prep(
    const float* __restrict__ W, int O, int K, int Opad, int Kp,
    u16* __restrict__ hi, u16* __restrict__ lo, float* __restrict__ wn)
{
  __shared__ float red[2];
  int o = blockIdx.x, cc = blockIdx.y, t = threadIdx.x;
  const float* src = W + ((size_t)cc * O + o) * K;
  u16* dh = hi + ((size_t)cc * Opad + o) * Kp;
  u16* dl = lo + ((size_t)cc * Opad + o) * Kp;
  float p = 0.f;
  for (int k = t; k < Kp; k += 128) {
    float v = (o < O && k < K) ? src[k] : 0.f;
    u16 h = f2bf(v);
    u16 l = f2bf(v - bf2f(h));
    dh[k] = h; dl[k] = l;
    p = fmaf(v, v, p);
  }
  for (int off = 32; off; off >>= 1) p += __shfl_down(p, off, 64);
  if ((t & 63) == 0) red[t >> 6] = p;
  __syncthreads();
  if (t == 0) wn[(size_t)cc * Opad + o] = red[0] + red[1];
}

// ---------------- L1 GEMM pass: fused patch extraction + MFMA + d^2 store ----------------
__global__ __launch_bounds__(256) void l1_gemm_d2(
    const float* __restrict__ x, int c,
    const u16* __restrict__ Wh, const u16* __restrict__ Wl,
    const float* __restrict__ wn, float* __restrict__ dist1)
{
  __shared__ __align__(16) u16 sm[16384];
  __shared__ float img[1568];
  __shared__ float pnsm[512];
  __shared__ float pnloc[128];
  const int t = threadIdx.x;
  const int w = t >> 6, lane = t & 63;
  const int b0 = blockIdx.x * 2;

  {
    const int kk = (w & 3) * 8;
#pragma unroll
    for (int u = 0; u < 2; ++u) {
      const size_t gb = (size_t)(u * 64 + lane) * 32 + kk;
      const int ls = ((w & 3) * 128 + u * 64) * 8;
      gload16(Wh + gb, sm + 8192 + ls);
      gload16(Wl + gb, sm + 12288 + ls);
    }
  }
#pragma unroll
  for (int im = 0; im < 2; ++im) {
    if (t < 196)
      ((float4*)(img + im * 784))[t] =
          ((const float4*)(x + ((size_t)(b0 + im) * 3 + c) * 784))[t];
  }
  __syncthreads();
  for (int s = t; s < 512; s += 256) {
    int q = s >> 7, row = s & 127;
    int im = row >> 6, pr = row & 63;
    int pi = pr / 6, pj = pr - pi * 6;
    const float* ib = img + im * 784 + pi * 4 * 28 + pj * 4;
    float v[8]; float pn = 0.f;
#pragma unroll
    for (int e = 0; e < 8; ++e) {
      int k = q * 8 + e;
      float val = 0.f;
      if (pr < 36 && k < 25) { int r = k / 5, ss = k - r * 5; val = ib[r * 28 + ss]; }
      v[e] = val; pn = fmaf(val, val, pn);
    }
    u16 hi8[8], lo8[8];
#pragma unroll
    for (int e = 0; e < 8; ++e) {
      u16 h = f2bf(v[e]); hi8[e] = h; lo8[e] = f2bf(v[e] - bf2f(h));
    }
    *(bf16x8*)(sm + (q * 128 + row) * 8) = *(bf16x8*)hi8;
    *(bf16x8*)(sm + 4096 + (q * 128 + row) * 8) = *(bf16x8*)lo8;
    pnsm[s] = pn;
  }
  asm volatile("s_waitcnt vmcnt(0)" ::: "memory");
  __syncthreads();
  if (t < 128) pnloc[t] = pnsm[t] + pnsm[128 + t] + pnsm[256 + t] + pnsm[384 + t];

  const int wr = w >> 1, wc = w & 1;
  const int q4 = lane >> 4, r16 = lane & 15;
  f32x4 accv[4][4];
#pragma unroll
  for (int i = 0; i < 4; ++i)
#pragma unroll
    for (int j = 0; j < 4; ++j) accv[i][j] = (f32x4){0.f, 0.f, 0.f, 0.f};

  bf16x8 Ah[4], Al[4], Bh[4], Bl[4];
#pragma unroll
  for (int i = 0; i < 4; ++i) {
    int ao = (q4 * 128 + wr * 64 + i * 16 + r16) * 8;
    int bo = (q4 * 128 + wc * 64 + i * 16 + r16) * 8;
    Ah[i] = *(const bf16x8*)(sm + ao);
    Al[i] = *(const bf16x8*)(sm + 4096 + ao);
    Bh[i] = *(const bf16x8*)(sm + 8192 + bo);
    Bl[i] = *(const bf16x8*)(sm + 12288 + bo);
  }
#pragma unroll
  for (int i = 0; i < 4; ++i)
#pragma unroll
    for (int j = 0; j < 4; ++j) {
      accv[i][j] = __builtin_amdgcn_mfma_f32_16x16x32_bf16(Ah[i], Bh[j], accv[i][j], 0, 0, 0);
      accv[i][j] = __builtin_amdgcn_mfma_f32_16x16x32_bf16(Al[i], Bh[j], accv[i][j], 0, 0, 0);
      accv[i][j] = __builtin_amdgcn_mfma_f32_16x16x32_bf16(Ah[i], Bl[j], accv[i][j], 0, 0, 0);
    }
  __syncthreads();

  int colv[4]; float wnv[4];
#pragma unroll
  for (int j = 0; j < 4; ++j) {
    colv[j] = wc * 64 + j * 16 + r16;
    wnv[j] = (colv[j] < 100) ? wn[colv[j]] : 0.f;
  }
#pragma unroll
  for (int i = 0; i < 4; ++i) {
#pragma unroll
    for (int r = 0; r < 4; ++r) {
      int pos = i * 16 + q4 * 4 + r;
      if (pos < 36) {
        float pn = pnloc[wr * 64 + pos];
        float* drow = dist1 + ((size_t)(b0 + wr) * 36 + pos) * 100;
#pragma unroll
        for (int j = 0; j < 4; ++j) {
          if (colv[j] < 100) {
            float d2 = pn + wnv[j] - 2.f * accv[i][j][r];
            drow[colv[j]] = fmaxf(d2, 0.f) + 1e-12f;
          }
        }
      }
    }
  }
}

// ---------------- L1 std reduce: d^2 -> per-(pos,stripe) s/q partials ----------------
__global__ __launch_bounds__(256) void l1_reduce_bw(
    const float* __restrict__ d1, int B, float* __restrict__ part)
{
  __shared__ float sh[8];
  int pos = blockIdx.x, stripe = blockIdx.y, t = threadIdx.x;
  int ch = t & 127, bsub = t >> 7;
  float s = 0.f, q = 0.f;
  if (ch < 100) {
    int nb = B / 64;
    for (int bi = bsub; bi < nb; bi += 2) {
      float v = d1[((size_t)(bi * 64 + stripe) * 36 + pos) * 100 + ch];
      s += fsqrt(v); q += v;
    }
  }
  for (int off = 32; off; off >>= 1) {
    s += __shfl_down(s, off, 64);
    q += __shfl_down(q, off, 64);
  }
  if ((t & 63) == 0) { sh[(t >> 6) * 2] = s; sh[(t >> 6) * 2 + 1] = q; }
  __syncthreads();
  if (t == 0) {
    s = sh[0] + sh[2] + sh[4] + sh[6];
    q = sh[1] + sh[3] + sh[5] + sh[7];
    part[pos * STRIPES + stripe] = s;
    part[(36 + pos) * STRIPES + stripe] = q;
  }
}

__global__ __launch_bounds__(256) void l1_part_fin(
    const float* __restrict__ part, int NB, float* __restrict__ inv36, double n)
{
  __shared__ double sh[8];
  int pos = blockIdx.x, t = threadIdx.x;
  double s = 0.0, q = 0.0;
  for (int b = t; b < NB; b += 256) {
    s += part[(size_t)pos * NB + b];
    q += part[(size_t)(36 + pos) * NB + b];
  }
  for (int off = 32; off; off >>= 1) {
    s += __shfl_down(s, off, 64);
    q += __shfl_down(q, off, 64);
  }
  if ((t & 63) == 0) { sh[(t >> 6) * 2] = s; sh[(t >> 6) * 2 + 1] = q; }
  __syncthreads();
  if (t == 0) {
    s = sh[0] + sh[2] + sh[4] + sh[6];
    q = sh[1] + sh[3] + sh[5] + sh[7];
    double var = (q - s * s / n) / (n - 1.0);
    inv36[pos] = var > 0.0 ? (float)(0.5 / var) : __builtin_inff();
  }
}

// ---------------- L1 sfm: d^2 -> exp/crelu -> 2x2 alpha-pool -> X hi/lo + xn ----------------
__global__ __launch_bounds__(128) void l1_sfm_lite(
    const float* __restrict__ d1, const float* __restrict__ inv36,
    const float* __restrict__ cb,
    u16* __restrict__ Xhi, u16* __restrict__ Xlo, float* __restrict__ xn)
{
  __shared__ float inv_s[36];
  __shared__ float xnsm[9][2];
  int b = blockIdx.x, t = threadIdx.x;
  if (t < 36) inv_s[t] = inv36[t];
  __syncthreads();
  const float* db = d1 + (size_t)b * 3600;
  float bias = cb[0];
  int wv = t >> 6;
#pragma unroll
  for (int IJ = 0; IJ < 9; ++IJ) {
    const int I = IJ / 3, J = IJ - I * 3;
    const int p00 = 12 * I + 2 * J;
    float v = 0.f;
    if (t < 100) {
      float e00 = fexp(-db[p00 * 100 + t] * inv_s[p00]);
      float e01 = fexp(-db[(p00 + 1) * 100 + t] * inv_s[p00 + 1]);
      float e10 = fexp(-db[(p00 + 6) * 100 + t] * inv_s[p00 + 6]);
      float e11 = fexp(-db[(p00 + 7) * 100 + t] * inv_s[p00 + 7]);
      e00 = (e00 >= bias) ? e00 : 0.f;
      e01 = (e01 >= bias) ? e01 : 0.f;
      e10 = (e10 >= bias) ? e10 : 0.f;
      e11 = (e11 >= bias) ? e11 : 0.f;
      v = 0.25f * (fmaf(0.729f, e00, 0.81f * e01) + fmaf(0.9f, e10, e11));
    }
    size_t xrow = (size_t)b * 9 + IJ;
    u16 h = f2bf(v);
    u16 l = f2bf(v - bf2f(h));
    Xhi[xrow * 128 + t] = h;
    Xlo[xrow * 128 + t] = l;
    float p = v * v;
    for (int off = 32; off; off >>= 1) p += __shfl_down(p, off, 64);
    if ((t & 63) == 0) xnsm[IJ][wv] = p;
  }
  __syncthreads();
  if (t < 9) xn[(size_t)b * 9 + t] = xnsm[t][0] + xnsm[t][1];
}

// ---------------- 256x256-tile 8-wave pipelined split-bf16 MFMA cdist GEMM ----------------
// Double-buffered LDS (2 x 64 KB) with raw s_barrier: prefetch for step k+1
// stays in flight across the compute of step k (compiler __syncthreads would
// drain vmcnt(0) and serialize). One block/CU; pipeline replaces cross-block
// overlap. dist holds squared distances (+eps).
__global__ __launch_bounds__(512, 2) void gemm_dist_pipe(
    const u16* __restrict__ Xhi, const u16* __restrict__ Xlo,
    const u16* __restrict__ Whi, const u16* __restrict__ Wlo,
    const float* __restrict__ xn, const float* __restrict__ wn,
    float* __restrict__ dist, int O, int Kp,
    double* __restrict__ acc, int accbase, int c0,
    int sXc, int sWc, int sxnc, int swnc, int sdistc)
{
  __shared__ __align__(16) u16 sm[65536];   // 128 KB: buffers at 0 and 32768
  int zi = blockIdx.z, c = c0 + zi;
  Xhi += (size_t)zi * sXc; Xlo += (size_t)zi * sXc;
  Whi += (size_t)c * sWc;  Wlo += (size_t)c * sWc;
  xn += (size_t)zi * sxnc; wn += (size_t)c * swnc;
  dist += (size_t)zi * sdistc;
  acc += (size_t)c * ACC_TOTAL;

  const int t = threadIdx.x;
  const int w = t >> 6, lane = t & 63;
  const int wr = w >> 1, wc = w & 1;
  const int sq = w & 3, half = w >> 2;
  const int m0 = blockIdx.x * 256, o0 = blockIdx.y * 256;
  const int q4 = lane >> 4, r16 = lane & 15;
  const int nsteps = Kp / 32;

  f32x4 accv[4][8];
#pragma unroll
  for (int i = 0; i < 4; ++i)
#pragma unroll
    for (int j = 0; j < 8; ++j) accv[i][j] = (f32x4){0.f, 0.f, 0.f, 0.f};

  // staging: wave (sq,half) loads k-chunk sq, row-halves; 8 gload16/wave/step
  auto stage = [&](int buf, int ks) {
    const int kk = ks * 32 + sq * 8;
    u16* base = sm + buf * 32768;
#pragma unroll
    for (int u = 0; u < 2; ++u) {
      const int row = half * 128 + u * 64 + lane;
      const size_t ga = (size_t)(m0 + row) * Kp + kk;
      const size_t gb = (size_t)(o0 + row) * Kp + kk;
      const int ls = (sq * 256 + half * 128 + u * 64) * 8;
      gload16(Xhi + ga, base + ls);
      gload16(Xlo + ga, base + 8192 + ls);
      gload16(Whi + gb, base + 16384 + ls);
      gload16(Wlo + gb, base + 24576 + ls);
    }
  };

  stage(0, 0);   // prologue
  for (int ks = 0; ks < nsteps; ++ks) {
    // current buffer's 8 loads are the only outstanding ones -> drain + sync
    asm volatile("s_waitcnt vmcnt(0)\n\ts_barrier" ::: "memory");
    if (ks + 1 < nsteps) stage((ks + 1) & 1, ks + 1);   // prefetch, stays in flight
    const u16* base = sm + (ks & 1) * 32768;

    bf16x8 Ah[4], Al[4];
#pragma unroll
    for (int i = 0; i < 4; ++i) {
      int ao = (q4 * 256 + wr * 64 + i * 16 + r16) * 8;
      Ah[i] = *(const bf16x8*)(base + ao);
      Al[i] = *(const bf16x8*)(base + 8192 + ao);
    }
#pragma unroll
    for (int j = 0; j < 8; ++j) {
      int bo = (q4 * 256 + wc * 128 + j * 16 + r16) * 8;
      bf16x8 Bh = *(const bf16x8*)(base + 16384 + bo);
      bf16x8 Bl = *(const bf16x8*)(base + 24576 + bo);
#pragma unroll
      for (int i = 0; i < 4; ++i) {
        accv[i][j] = __builtin_amdgcn_mfma_f32_16x16x32_bf16(Ah[i], Bh, accv[i][j], 0, 0, 0);
        accv[i][j] = __builtin_amdgcn_mfma_f32_16x16x32_bf16(Al[i], Bh, accv[i][j], 0, 0, 0);
        accv[i][j] = __builtin_amdgcn_mfma_f32_16x16x32_bf16(Ah[i], Bl, accv[i][j], 0, 0, 0);
      }
    }
    // bare barrier: all waves done reading buf ks&1; prefetch loads (other
    // buffer) remain in flight. ds_reads are consumed (lgkm drained before MFMA).
    asm volatile("s_barrier" ::: "memory");
  }

  double s = 0.0, qd = 0.0;
#pragma unroll
  for (int i = 0; i < 4; ++i) {
    const int mb = m0 + wr * 64 + i * 16 + q4 * 4;
    float xnv[4];
#pragma unroll
    for (int r = 0; r < 4; ++r) xnv[r] = xn[mb + r];
    float sf = 0.f, qf = 0.f;
#pragma unroll
    for (int j = 0; j < 8; ++j) {
      const int o = o0 + wc * 128 + j * 16 + r16;
      if (o < O) {
        const float wnv = wn[o];
#pragma unroll
        for (int r = 0; r < 4; ++r) {
          float d2 = xnv[r] + wnv - 2.f * accv[i][j][r];
          float d2c = fmaxf(d2, 0.f) + 1e-12f;
          dist[(size_t)(mb + r) * O + o] = d2c;
          sf += fsqrt(d2c); qf += d2c;
        }
      }
    }
    s += sf; qd += qf;
  }
  for (int off = 32; off; off >>= 1) {
    s += __shfl_down(s, off, 64);
    qd += __shfl_down(qd, off, 64);
  }
  double* redsm = (double*)sm;
  if (lane == 0) { redsm[w * 2] = s; redsm[w * 2 + 1] = qd; }
  __syncthreads();
  if (t == 0) {
    s = 0.0; qd = 0.0;
#pragma unroll
    for (int ww = 0; ww < 8; ++ww) { s += redsm[ww * 2]; qd += redsm[ww * 2 + 1]; }
    int stripe = (blockIdx.x + blockIdx.y * gridDim.x) & (STRIPES - 1);
    atomicAdd(&acc[accbase + stripe * 2], s);
    atomicAdd(&acc[accbase + stripe * 2 + 1], qd);
  }
}

__device__ __forceinline__ float block_inv_from_acc(
    const double* __restrict__ acc, int base, double n, float* sh)
{
  __syncthreads();
  int t = threadIdx.x;
  if (t < 64) {
    double s = acc[base + 2 * t], q = acc[base + 2 * t + 1];
    for (int off = 32; off; off >>= 1) {
      s += __shfl_down(s, off, 64);
      q += __shfl_down(q, off, 64);
    }
    if (t == 0) {
      double var = (q - s * s / n) / (n - 1.0);
      *sh = var > 0.0 ? (float)(0.5 / var) : __builtin_inff();
    }
  }
  __syncthreads();
  return *sh;
}

// exp -> crelu(cb1) -> [0.81,0.9,1]/3 pool -> hi/lo (Kp=256) + xn   (dist2 = d^2)
__global__ __launch_bounds__(256) void l2_sfm(
    const float* __restrict__ dist2, const double* __restrict__ acc, double n,
    const float* __restrict__ cb, u16* __restrict__ Xhi, u16* __restrict__ Xlo,
    float* __restrict__ xn, int c0, int sdistc, int sXc, int sxnc)
{
  __shared__ float shinv;
  __shared__ float red[4];
  int zi = blockIdx.z, c = c0 + zi;
  dist2 += (size_t)zi * sdistc;
  Xhi += (size_t)zi * sXc; Xlo += (size_t)zi * sXc; xn += (size_t)zi * sxnc;
  float inv = block_inv_from_acc(acc + (size_t)c * ACC_TOTAL, ACC_L2, n, &shinv);
  int b = blockIdx.x, u = blockIdx.y, ch = threadIdx.x;
  float bias = cb[1];
  float v = 0.f;
  if (ch < 225) {
    const float av[3] = {0.81f, 0.9f, 1.0f};
    float a = 0.f;
#pragma unroll
    for (int vv = 0; vv < 3; ++vv) {
      float d2 = dist2[((size_t)b * 9 + u * 3 + vv) * 225 + ch];
      float e = fexp(-d2 * inv);
      e = (e >= bias) ? e : 0.f;
      a = fmaf(e, av[vv], a);
    }
    v = a * (1.f / 3.f);
  }
  size_t row = (size_t)b * 3 + u;
  u16 h = f2bf(v);
  u16 l = f2bf(v - bf2f(h));
  Xhi[row * 256 + ch] = h;
  Xlo[row * 256 + ch] = l;
  float p = v * v;
  for (int off = 32; off; off >>= 1) p += __shfl_down(p, off, 64);
  if ((ch & 63) == 0) red[ch >> 6] = p;
  __syncthreads();
  if (ch == 0) xn[row] = red[0] + red[1] + red[2] + red[3];
}

// exp -> crelu(cb2) -> [0.81,0.9,1]/3 pool -> hi/lo (Kp=640) + xn   (dist3 = d^2)
__global__ __launch_bounds__(256) void l3_sfm(
    const float* __restrict__ dist3, const double* __restrict__ acc, double n,
    const float* __restrict__ cb, u16* __restrict__ Xhi, u16* __restrict__ Xlo,
    float* __restrict__ xn, int c0, int sdistc, int sXc, int sxnc)
{
  __shared__ float shinv;
  __shared__ float red[4];
  int zi = blockIdx.y, c = c0 + zi;
  dist3 += (size_t)zi * sdistc;
  Xhi += (size_t)zi * sXc; Xlo += (size_t)zi * sXc; xn += (size_t)zi * sxnc;
  float inv = block_inv_from_acc(acc + (size_t)c * ACC_TOTAL, ACC_L3, n, &shinv);
  int b = blockIdx.x, t = threadIdx.x;
  float bias = cb[2];
  const float au[3] = {0.81f, 0.9f, 1.0f};
  float p = 0.f;
  for (int ch = t; ch < 640; ch += 256) {
    float v = 0.f;
    if (ch < 625) {
      float a = 0.f;
#pragma unroll
      for (int u = 0; u < 3; ++u) {
        float d2 = dist3[((size_t)b * 3 + u) * 625 + ch];
        float e = fexp(-d2 * inv);
        e = (e >= bias) ? e : 0.f;
        a = fmaf(e, au[u], a);
      }
      v = a * (1.f / 3.f);
    }
    u16 h = f2bf(v);
    u16 l = f2bf(v - bf2f(h));
    Xhi[(size_t)b * 640 + ch] = h;
    Xlo[(size_t)b * 640 + ch] = l;
    p = fmaf(v, v, p);
  }
  for (int off = 32; off; off >>= 1) p += __shfl_down(p, off, 64);
  if ((t & 63) == 0) red[t >> 6] = p;
  __syncthreads();
  if (t == 0) xn[b] = red[0] + red[1] + red[2] + red[3];
}

// L4 exp/crelu fused into FC; loops nc channels internally  (dist4 = d^2)
__global__ __launch_bounds__(128) void fc_acc(
    const float* __restrict__ dist4, const double* __restrict__ acc, double n,
    const float* __restrict__ cb, const float* __restrict__ fcw,
    const float* __restrict__ fcb, float* __restrict__ out,
    int c0, int nc, int sdistc)
{
  __shared__ float shinv;
  int b = blockIdx.x, t = threadIdx.x;
  float bias = cb[3];
  float p[10];
#pragma unroll
  for (int k = 0; k < 10; ++k) p[k] = 0.f;
  for (int zi = 0; zi < nc; ++zi) {
    int c = c0 + zi;
    float inv = block_inv_from_acc(acc + (size_t)c * ACC_TOTAL, ACC_L4, n, &shinv);
    const float* d4 = dist4 + (size_t)zi * sdistc;
    for (int j = t; j < 1225; j += 128) {
      float d2 = d4[(size_t)b * 1225 + j];
      float v = fexp(-d2 * inv);
      v = (v >= bias) ? v : 0.f;
#pragma unroll
      for (int k = 0; k < 10; ++k) p[k] = fmaf(v, fcw[k * 3675 + c * 1225 + j], p[k]);
    }
  }
#pragma unroll
  for (int k = 0; k < 10; ++k)
    for (int off = 32; off; off >>= 1) p[k] += __shfl_down(p[k], off, 64);
  __shared__ float red[2][10];
  int wave = t >> 6;
  if ((t & 63) == 0) {
#pragma unroll
    for (int k = 0; k < 10; ++k) red[wave][k] = p[k];
  }
  __syncthreads();
  if (t < 10) {
    float v = red[0][t] + red[1][t];
    if (c0 == 0) out[(size_t)b * 10 + t] = fcb[t] + v;
    else         out[(size_t)b * 10 + t] += v;
  }
}

extern "C" void kernel_launch(void* const* d_in, const int* in_sizes, int n_in,
                              void* d_out, int out_size, void* d_ws, size_t ws_size,
                              hipStream_t stream) {
  const float* x   = (const float*)d_in[0];
  const float* w1  = (const float*)d_in[1];
  const float* w2  = (const float*)d_in[2];
  const float* w3  = (const float*)d_in[3];
  const float* w4  = (const float*)d_in[4];
  const float* fcw = (const float*)d_in[5];
  const float* fcb = (const float*)d_in[6];
  const float* cb  = (const float*)d_in[7];
  float* out = (float*)d_out;
  const int B = in_sizes[0] / (3 * 28 * 28);   // 4096
  const int M2 = B * 9, M3 = B * 3;
  const int NB = B / 2;

  const size_t W2SZ = 256 * 128, W3SZ = 768 * 256, W4SZ = (size_t)1280 * 640;
  const size_t WTOT = 3 * (W2SZ + W3SZ + W4SZ);

  bool batched = true;
  u16 *Xbase, *Whi, *Wlo, *W1h, *W1l;
  float *wn, *w1n, *xn, *inv36, *part;
  double* accd;
  float* Sf;
  for (int attempt = 0; attempt < 2; ++attempt) {
    size_t cur = 0;
    char* basep = (char*)d_ws;
    auto take = [&](size_t bytes) {
      void* r = basep + cur;
      cur = (cur + bytes + 255) & ~(size_t)255;
      return r;
    };
    int nc = batched ? 3 : 1;
    size_t Ssz = (size_t)M2 * 225 * 4 * nc;          // dist2 (largest batched)
    size_t d1sz = (size_t)B * 3600 * 4;              // L1 d^2 (single channel)
    if (d1sz > Ssz) Ssz = d1sz;
    Sf = (float*)take(Ssz);
    Xbase = (u16*)take((size_t)M2 * 128 * 2 * 2 * nc);
    Whi = (u16*)take(WTOT * 2); Wlo = (u16*)take(WTOT * 2);
    W1h = (u16*)take(12288 * 2); W1l = (u16*)take(12288 * 2);
    wn  = (float*)take(3 * (256 + 768 + 1280) * 4);
    w1n = (float*)take(384 * 4);
    xn    = (float*)take((size_t)M2 * 4 * nc);
    inv36 = (float*)take(40 * 4);
    part  = (float*)take(72 * STRIPES * 4);
    accd  = (double*)take(3 * ACC_TOTAL * 8);
    if (cur <= ws_size) break;
    batched = false;
  }
  const int nc = batched ? 3 : 1;

  const int sX2c   = batched ? M2 * 128 * 2 : 0;
  const int sX3c   = batched ? M3 * 256 * 2 : 0;
  const int sX4c   = batched ? B * 640 * 2 : 0;
  const int sD2c   = batched ? M2 * 225 : 0;
  const int sD3c   = batched ? M3 * 625 : 0;
  const int sD4c   = batched ? B * 1225 : 0;
  const int sXn2c  = batched ? M2 : 0;
  const int sXn3c  = batched ? M3 : 0;
  const int sXn4c  = batched ? B : 0;

  u16* x2hi = Xbase;   u16* x2lo = Xbase + (size_t)M2 * 128;
  u16* x3hi = Xbase;   u16* x3lo = Xbase + (size_t)M3 * 256;
  u16* x4hi = Xbase;   u16* x4lo = Xbase + (size_t)B * 640;
  u16* Whi2 = Whi;                 u16* Wlo2 = Wlo;                 float* wn2 = wn;
  u16* Whi3 = Whi + 3 * W2SZ;      u16* Wlo3 = Wlo + 3 * W2SZ;      float* wn3 = wn + 3 * 256;
  u16* Whi4 = Whi + 3 * (W2SZ + W3SZ); u16* Wlo4 = Wlo + 3 * (W2SZ + W3SZ);
  float* wn4 = wn + 3 * (256 + 768);

  zero_acc_kernel<<<(3 * ACC_TOTAL + 255) / 256, 256, 0, stream>>>(accd, 3 * ACC_TOTAL);
  w_prep<<<dim3(128, 3),  128, 0, stream>>>(w1, 100, 25,  128, 32,  W1h,  W1l,  w1n);
  w_prep<<<dim3(256, 3),  128, 0, stream>>>(w2, 225, 100, 256, 128, Whi2, Wlo2, wn2);
  w_prep<<<dim3(768, 3),  128, 0, stream>>>(w3, 625, 225, 768, 256, Whi3, Wlo3, wn3);
  w_prep<<<dim3(1280, 3), 128, 0, stream>>>(w4, 1225, 625, 1280, 640, Whi4, Wlo4, wn4);

  for (int c0 = 0; c0 < 3; c0 += nc) {
    // ---- L1: channel-serial (d^2 buffer Sf reused per channel) ----
    for (int ci = 0; ci < nc; ++ci) {
      int c = c0 + ci;
      l1_gemm_d2<<<NB, 256, 0, stream>>>(
          x, c, W1h + (size_t)c * 4096, W1l + (size_t)c * 4096, w1n + (size_t)c * 128, Sf);
      l1_reduce_bw<<<dim3(36, STRIPES), 256, 0, stream>>>(Sf, B, part);
      l1_part_fin<<<36, 256, 0, stream>>>(part, STRIPES, inv36, (double)B * 100.0);
      l1_sfm_lite<<<B, 128, 0, stream>>>(
          Sf, inv36, cb, x2hi + (size_t)ci * sX2c, x2lo + (size_t)ci * sX2c,
          xn + (size_t)ci * sXn2c);
    }

    // L2: (M2 x 128) x (256 x 128) -> dist2 (M2 x 225)
    gemm_dist_pipe<<<dim3(M2 / 256, 1, nc), 512, 0, stream>>>(
        x2hi, x2lo, Whi2, Wlo2, xn, wn2, Sf, 225, 128, accd, ACC_L2, c0,
        sX2c, (int)W2SZ, sXn2c, 256, sD2c);
    l2_sfm<<<dim3(B, 3, nc), 256, 0, stream>>>(
        Sf, accd, (double)M2 * 225.0, cb, x3hi, x3lo, xn, c0, sD2c, sX3c, sXn3c);

    // L3: (M3 x 256) x (768 x 256) -> dist3 (M3 x 625)
    gemm_dist_pipe<<<dim3(M3 / 256, 3, nc), 512, 0, stream>>>(
        x3hi, x3lo, Whi3, Wlo3, xn, wn3, Sf, 625, 256, accd, ACC_L3, c0,
        sX3c, (int)W3SZ, sXn3c, 768, sD3c);
    l3_sfm<<<dim3(B, nc), 256, 0, stream>>>(
        Sf, accd, (double)M3 * 625.0, cb, x4hi, x4lo, xn, c0, sD3c, sX4c, sXn4c);

    // L4: (B x 640) x (1280 x 640) -> dist4 (B x 1225)
    gemm_dist_pipe<<<dim3(B / 256, 5, nc), 512, 0, stream>>>(
        x4hi, x4lo, Whi4, Wlo4, xn, wn4, Sf, 1225, 640, accd, ACC_L4, c0,
        sX4c, (int)W4SZ, sXn4c, 1280, sD4c);
    fc_acc<<<B, 128, 0, stream>>>(
        Sf, accd, (double)B * 1225.0, cb, fcw, fcb, out, c0, nc, sD4c);
  }
}

// Round 10
// 528.576 us; speedup vs baseline: 1.1433x; 1.0671x over previous
//
#include <hip/hip_runtime.h>

// SOMNetwork forward. All four rbf/cdist layers via split-bf16 MFMA GEMM
// (hi/lo decomposition, 3 MFMAs/product).
// L1: single GEMM pass writes d^2 (L3-resident) + BW-bound std-reduce and sfm
// kernels; round 10: L1 chain batched across channels (tier-0 ws plan,
// 177 MB d1 buffer) -> 4 dispatches instead of 12.
// L2/L3/L4: 256x256-tile 8-wave pipelined GEMM (raw s_barrier double-buffer);
// round 10: pass-major MFMA order (4 independent MFMAs between dependent ones).
// Channels batched into grid z. Tiered ws fallback keeps old plans valid.

typedef unsigned short u16;
typedef short bf16x8 __attribute__((ext_vector_type(8)));
typedef float f32x4 __attribute__((ext_vector_type(4)));

#define STRIPES 64
#define ACC_L2 0            // 64 stripes * 2 doubles per layer region
#define ACC_L3 128
#define ACC_L4 256
#define ACC_TOTAL 384

__device__ __forceinline__ u16 f2bf(float f) {
  unsigned int u = __float_as_uint(f);
  unsigned int r = (u + 0x7fffu + ((u >> 16) & 1u)) >> 16;
  return (u16)r;
}
__device__ __forceinline__ float bf2f(u16 h) {
  return __uint_as_float(((unsigned int)h) << 16);
}
__device__ __forceinline__ float fexp(float x) { return __expf(x); }
__device__ __forceinline__ float fsqrt(float x) { return __builtin_amdgcn_sqrtf(x); }
__device__ __forceinline__ void gload16(const void* g, const void* l) {
  __builtin_amdgcn_global_load_lds(
      (const __attribute__((address_space(1))) unsigned int*)g,
      (__attribute__((address_space(3))) unsigned int*)l, 16, 0, 0);
}

__global__ void zero_acc_kernel(double* __restrict__ acc, int n) {
  int i = blockIdx.x * blockDim.x + threadIdx.x;
  if (i < n) acc[i] = 0.0;
}

// ---------------- weight prep: fp32 -> hi/lo bf16 (padded) + row norms ----------------
__global__ __launch_bounds__(128) void w_prep(
    const float* __restrict__ W, int O, int K, int Opad, int Kp,
    u16* __restrict__ hi, u16* __restrict__ lo, float* __restrict__ wn)
{
  __shared__ float red[2];
  int o = blockIdx.x, cc = blockIdx.y, t = threadIdx.x;
  const float* src = W + ((size_t)cc * O + o) * K;
  u16* dh = hi + ((size_t)cc * Opad + o) * Kp;
  u16* dl = lo + ((size_t)cc * Opad + o) * Kp;
  float p = 0.f;
  for (int k = t; k < Kp; k += 128) {
    float v = (o < O && k < K) ? src[k] : 0.f;
    u16 h = f2bf(v);
    u16 l = f2bf(v - bf2f(h));
    dh[k] = h; dl[k] = l;
    p = fmaf(v, v, p);
  }
  for (int off = 32; off; off >>= 1) p += __shfl_down(p, off, 64);
  if ((t & 63) == 0) red[t >> 6] = p;
  __syncthreads();
  if (t == 0) wn[(size_t)cc * Opad + o] = red[0] + red[1];
}

// ---------------- L1 GEMM pass: fused patch extraction + MFMA + d^2 store ----------------
// grid.y = channel index zi (c = c0 + zi); dist1 stride sD1c.
__global__ __launch_bounds__(256) void l1_gemm_d2(
    const float* __restrict__ x, int c0,
    const u16* __restrict__ W1h, const u16* __restrict__ W1l,
    const float* __restrict__ w1n, float* __restrict__ dist1, int sD1c)
{
  __shared__ __align__(16) u16 sm[16384];
  __shared__ float img[1568];
  __shared__ float pnsm[512];
  __shared__ float pnloc[128];
  const int t = threadIdx.x;
  const int w = t >> 6, lane = t & 63;
  const int b0 = blockIdx.x * 2;
  const int zi = blockIdx.y, c = c0 + zi;
  const u16* Wh = W1h + (size_t)c * 4096;
  const u16* Wl = W1l + (size_t)c * 4096;
  const float* wn = w1n + (size_t)c * 128;
  dist1 += (size_t)zi * sD1c;

  {
    const int kk = (w & 3) * 8;
#pragma unroll
    for (int u = 0; u < 2; ++u) {
      const size_t gb = (size_t)(u * 64 + lane) * 32 + kk;
      const int ls = ((w & 3) * 128 + u * 64) * 8;
      gload16(Wh + gb, sm + 8192 + ls);
      gload16(Wl + gb, sm + 12288 + ls);
    }
  }
#pragma unroll
  for (int im = 0; im < 2; ++im) {
    if (t < 196)
      ((float4*)(img + im * 784))[t] =
          ((const float4*)(x + ((size_t)(b0 + im) * 3 + c) * 784))[t];
  }
  __syncthreads();
  for (int s = t; s < 512; s += 256) {
    int q = s >> 7, row = s & 127;
    int im = row >> 6, pr = row & 63;
    int pi = pr / 6, pj = pr - pi * 6;
    const float* ib = img + im * 784 + pi * 4 * 28 + pj * 4;
    float v[8]; float pn = 0.f;
#pragma unroll
    for (int e = 0; e < 8; ++e) {
      int k = q * 8 + e;
      float val = 0.f;
      if (pr < 36 && k < 25) { int r = k / 5, ss = k - r * 5; val = ib[r * 28 + ss]; }
      v[e] = val; pn = fmaf(val, val, pn);
    }
    u16 hi8[8], lo8[8];
#pragma unroll
    for (int e = 0; e < 8; ++e) {
      u16 h = f2bf(v[e]); hi8[e] = h; lo8[e] = f2bf(v[e] - bf2f(h));
    }
    *(bf16x8*)(sm + (q * 128 + row) * 8) = *(bf16x8*)hi8;
    *(bf16x8*)(sm + 4096 + (q * 128 + row) * 8) = *(bf16x8*)lo8;
    pnsm[s] = pn;
  }
  asm volatile("s_waitcnt vmcnt(0)" ::: "memory");
  __syncthreads();
  if (t < 128) pnloc[t] = pnsm[t] + pnsm[128 + t] + pnsm[256 + t] + pnsm[384 + t];

  const int wr = w >> 1, wc = w & 1;
  const int q4 = lane >> 4, r16 = lane & 15;
  f32x4 accv[4][4];
#pragma unroll
  for (int i = 0; i < 4; ++i)
#pragma unroll
    for (int j = 0; j < 4; ++j) accv[i][j] = (f32x4){0.f, 0.f, 0.f, 0.f};

  bf16x8 Ah[4], Al[4], Bh[4], Bl[4];
#pragma unroll
  for (int i = 0; i < 4; ++i) {
    int ao = (q4 * 128 + wr * 64 + i * 16 + r16) * 8;
    int bo = (q4 * 128 + wc * 64 + i * 16 + r16) * 8;
    Ah[i] = *(const bf16x8*)(sm + ao);
    Al[i] = *(const bf16x8*)(sm + 4096 + ao);
    Bh[i] = *(const bf16x8*)(sm + 8192 + bo);
    Bl[i] = *(const bf16x8*)(sm + 12288 + bo);
  }
#pragma unroll
  for (int j = 0; j < 4; ++j) {
#pragma unroll
    for (int i = 0; i < 4; ++i)
      accv[i][j] = __builtin_amdgcn_mfma_f32_16x16x32_bf16(Ah[i], Bh[j], accv[i][j], 0, 0, 0);
#pragma unroll
    for (int i = 0; i < 4; ++i)
      accv[i][j] = __builtin_amdgcn_mfma_f32_16x16x32_bf16(Al[i], Bh[j], accv[i][j], 0, 0, 0);
#pragma unroll
    for (int i = 0; i < 4; ++i)
      accv[i][j] = __builtin_amdgcn_mfma_f32_16x16x32_bf16(Ah[i], Bl[j], accv[i][j], 0, 0, 0);
  }
  __syncthreads();

  int colv[4]; float wnv[4];
#pragma unroll
  for (int j = 0; j < 4; ++j) {
    colv[j] = wc * 64 + j * 16 + r16;
    wnv[j] = (colv[j] < 100) ? wn[colv[j]] : 0.f;
  }
#pragma unroll
  for (int i = 0; i < 4; ++i) {
#pragma unroll
    for (int r = 0; r < 4; ++r) {
      int pos = i * 16 + q4 * 4 + r;
      if (pos < 36) {
        float pn = pnloc[wr * 64 + pos];
        float* drow = dist1 + ((size_t)(b0 + wr) * 36 + pos) * 100;
#pragma unroll
        for (int j = 0; j < 4; ++j) {
          if (colv[j] < 100) {
            float d2 = pn + wnv[j] - 2.f * accv[i][j][r];
            drow[colv[j]] = fmaxf(d2, 0.f) + 1e-12f;
          }
        }
      }
    }
  }
}

// ---------------- L1 std reduce: d^2 -> per-(pos,stripe) s/q partials ----------------
__global__ __launch_bounds__(256) void l1_reduce_bw(
    const float* __restrict__ d1, int sD1c, int B, float* __restrict__ part, int sPartc)
{
  __shared__ float sh[8];
  int pos = blockIdx.x, stripe = blockIdx.y, zi = blockIdx.z, t = threadIdx.x;
  d1 += (size_t)zi * sD1c; part += (size_t)zi * sPartc;
  int ch = t & 127, bsub = t >> 7;
  float s = 0.f, q = 0.f;
  if (ch < 100) {
    int nb = B / 64;
    for (int bi = bsub; bi < nb; bi += 2) {
      float v = d1[((size_t)(bi * 64 + stripe) * 36 + pos) * 100 + ch];
      s += fsqrt(v); q += v;
    }
  }
  for (int off = 32; off; off >>= 1) {
    s += __shfl_down(s, off, 64);
    q += __shfl_down(q, off, 64);
  }
  if ((t & 63) == 0) { sh[(t >> 6) * 2] = s; sh[(t >> 6) * 2 + 1] = q; }
  __syncthreads();
  if (t == 0) {
    s = sh[0] + sh[2] + sh[4] + sh[6];
    q = sh[1] + sh[3] + sh[5] + sh[7];
    part[pos * STRIPES + stripe] = s;
    part[(36 + pos) * STRIPES + stripe] = q;
  }
}

__global__ __launch_bounds__(256) void l1_part_fin(
    const float* __restrict__ part, int sPartc, float* __restrict__ inv36, int sInvc,
    double n)
{
  __shared__ double sh[8];
  int pos = blockIdx.x, zi = blockIdx.y, t = threadIdx.x;
  part += (size_t)zi * sPartc; inv36 += (size_t)zi * sInvc;
  double s = 0.0, q = 0.0;
  for (int b = t; b < STRIPES; b += 256) {
    s += part[(size_t)pos * STRIPES + b];
    q += part[(size_t)(36 + pos) * STRIPES + b];
  }
  for (int off = 32; off; off >>= 1) {
    s += __shfl_down(s, off, 64);
    q += __shfl_down(q, off, 64);
  }
  if ((t & 63) == 0) { sh[(t >> 6) * 2] = s; sh[(t >> 6) * 2 + 1] = q; }
  __syncthreads();
  if (t == 0) {
    s = sh[0] + sh[2] + sh[4] + sh[6];
    q = sh[1] + sh[3] + sh[5] + sh[7];
    double var = (q - s * s / n) / (n - 1.0);
    inv36[pos] = var > 0.0 ? (float)(0.5 / var) : __builtin_inff();
  }
}

// ---------------- L1 sfm: d^2 -> exp/crelu -> 2x2 alpha-pool -> X hi/lo + xn ----------------
__global__ __launch_bounds__(128) void l1_sfm_lite(
    const float* __restrict__ d1, int sD1c,
    const float* __restrict__ inv36, int sInvc, const float* __restrict__ cb,
    u16* __restrict__ Xhi, u16* __restrict__ Xlo, float* __restrict__ xn,
    int sXc, int sxnc)
{
  __shared__ float inv_s[36];
  __shared__ float xnsm[9][2];
  int b = blockIdx.x, zi = blockIdx.y, t = threadIdx.x;
  d1 += (size_t)zi * sD1c; inv36 += (size_t)zi * sInvc;
  Xhi += (size_t)zi * sXc; Xlo += (size_t)zi * sXc; xn += (size_t)zi * sxnc;
  if (t < 36) inv_s[t] = inv36[t];
  __syncthreads();
  const float* db = d1 + (size_t)b * 3600;
  float bias = cb[0];
  int wv = t >> 6;
#pragma unroll
  for (int IJ = 0; IJ < 9; ++IJ) {
    const int I = IJ / 3, J = IJ - I * 3;
    const int p00 = 12 * I + 2 * J;
    float v = 0.f;
    if (t < 100) {
      float e00 = fexp(-db[p00 * 100 + t] * inv_s[p00]);
      float e01 = fexp(-db[(p00 + 1) * 100 + t] * inv_s[p00 + 1]);
      float e10 = fexp(-db[(p00 + 6) * 100 + t] * inv_s[p00 + 6]);
      float e11 = fexp(-db[(p00 + 7) * 100 + t] * inv_s[p00 + 7]);
      e00 = (e00 >= bias) ? e00 : 0.f;
      e01 = (e01 >= bias) ? e01 : 0.f;
      e10 = (e10 >= bias) ? e10 : 0.f;
      e11 = (e11 >= bias) ? e11 : 0.f;
      v = 0.25f * (fmaf(0.729f, e00, 0.81f * e01) + fmaf(0.9f, e10, e11));
    }
    size_t xrow = (size_t)b * 9 + IJ;
    u16 h = f2bf(v);
    u16 l = f2bf(v - bf2f(h));
    Xhi[xrow * 128 + t] = h;
    Xlo[xrow * 128 + t] = l;
    float p = v * v;
    for (int off = 32; off; off >>= 1) p += __shfl_down(p, off, 64);
    if ((t & 63) == 0) xnsm[IJ][wv] = p;
  }
  __syncthreads();
  if (t < 9) xn[(size_t)b * 9 + t] = xnsm[t][0] + xnsm[t][1];
}

// ---------------- 256x256-tile 8-wave pipelined split-bf16 MFMA cdist GEMM ----------------
__global__ __launch_bounds__(512, 2) void gemm_dist_pipe(
    const u16* __restrict__ Xhi, const u16* __restrict__ Xlo,
    const u16* __restrict__ Whi, const u16* __restrict__ Wlo,
    const float* __restrict__ xn, const float* __restrict__ wn,
    float* __restrict__ dist, int O, int Kp,
    double* __restrict__ acc, int accbase, int c0,
    int sXc, int sWc, int sxnc, int swnc, int sdistc)
{
  __shared__ __align__(16) u16 sm[65536];   // 128 KB: buffers at 0 and 32768
  int zi = blockIdx.z, c = c0 + zi;
  Xhi += (size_t)zi * sXc; Xlo += (size_t)zi * sXc;
  Whi += (size_t)c * sWc;  Wlo += (size_t)c * sWc;
  xn += (size_t)zi * sxnc; wn += (size_t)c * swnc;
  dist += (size_t)zi * sdistc;
  acc += (size_t)c * ACC_TOTAL;

  const int t = threadIdx.x;
  const int w = t >> 6, lane = t & 63;
  const int wr = w >> 1, wc = w & 1;
  const int sq = w & 3, half = w >> 2;
  const int m0 = blockIdx.x * 256, o0 = blockIdx.y * 256;
  const int q4 = lane >> 4, r16 = lane & 15;
  const int nsteps = Kp / 32;

  f32x4 accv[4][8];
#pragma unroll
  for (int i = 0; i < 4; ++i)
#pragma unroll
    for (int j = 0; j < 8; ++j) accv[i][j] = (f32x4){0.f, 0.f, 0.f, 0.f};

  auto stage = [&](int buf, int ks) {
    const int kk = ks * 32 + sq * 8;
    u16* base = sm + buf * 32768;
#pragma unroll
    for (int u = 0; u < 2; ++u) {
      const int row = half * 128 + u * 64 + lane;
      const size_t ga = (size_t)(m0 + row) * Kp + kk;
      const size_t gb = (size_t)(o0 + row) * Kp + kk;
      const int ls = (sq * 256 + half * 128 + u * 64) * 8;
      gload16(Xhi + ga, base + ls);
      gload16(Xlo + ga, base + 8192 + ls);
      gload16(Whi + gb, base + 16384 + ls);
      gload16(Wlo + gb, base + 24576 + ls);
    }
  };

  stage(0, 0);
  for (int ks = 0; ks < nsteps; ++ks) {
    asm volatile("s_waitcnt vmcnt(0)\n\ts_barrier" ::: "memory");
    if (ks + 1 < nsteps) stage((ks + 1) & 1, ks + 1);
    const u16* base = sm + (ks & 1) * 32768;

    bf16x8 Ah[4], Al[4];
#pragma unroll
    for (int i = 0; i < 4; ++i) {
      int ao = (q4 * 256 + wr * 64 + i * 16 + r16) * 8;
      Ah[i] = *(const bf16x8*)(base + ao);
      Al[i] = *(const bf16x8*)(base + 8192 + ao);
    }
#pragma unroll
    for (int j = 0; j < 8; ++j) {
      int bo = (q4 * 256 + wc * 128 + j * 16 + r16) * 8;
      bf16x8 Bh = *(const bf16x8*)(base + 16384 + bo);
      bf16x8 Bl = *(const bf16x8*)(base + 24576 + bo);
      // pass-major: 4 independent MFMAs between dependent pairs; accumulation
      // order per accv[i][j] unchanged (hh, lh, hl).
#pragma unroll
      for (int i = 0; i < 4; ++i)
        accv[i][j] = __builtin_amdgcn_mfma_f32_16x16x32_bf16(Ah[i], Bh, accv[i][j], 0, 0, 0);
#pragma unroll
      for (int i = 0; i < 4; ++i)
        accv[i][j] = __builtin_amdgcn_mfma_f32_16x16x32_bf16(Al[i], Bh, accv[i][j], 0, 0, 0);
#pragma unroll
      for (int i = 0; i < 4; ++i)
        accv[i][j] = __builtin_amdgcn_mfma_f32_16x16x32_bf16(Ah[i], Bl, accv[i][j], 0, 0, 0);
    }
    asm volatile("s_barrier" ::: "memory");
  }

  double s = 0.0, qd = 0.0;
#pragma unroll
  for (int i = 0; i < 4; ++i) {
    const int mb = m0 + wr * 64 + i * 16 + q4 * 4;
    float xnv[4];
#pragma unroll
    for (int r = 0; r < 4; ++r) xnv[r] = xn[mb + r];
    float sf = 0.f, qf = 0.f;
#pragma unroll
    for (int j = 0; j < 8; ++j) {
      const int o = o0 + wc * 128 + j * 16 + r16;
      if (o < O) {
        const float wnv = wn[o];
#pragma unroll
        for (int r = 0; r < 4; ++r) {
          float d2 = xnv[r] + wnv - 2.f * accv[i][j][r];
          float d2c = fmaxf(d2, 0.f) + 1e-12f;
          dist[(size_t)(mb + r) * O + o] = d2c;
          sf += fsqrt(d2c); qf += d2c;
        }
      }
    }
    s += sf; qd += qf;
  }
  for (int off = 32; off; off >>= 1) {
    s += __shfl_down(s, off, 64);
    qd += __shfl_down(qd, off, 64);
  }
  double* redsm = (double*)sm;
  if (lane == 0) { redsm[w * 2] = s; redsm[w * 2 + 1] = qd; }
  __syncthreads();
  if (t == 0) {
    s = 0.0; qd = 0.0;
#pragma unroll
    for (int ww = 0; ww < 8; ++ww) { s += redsm[ww * 2]; qd += redsm[ww * 2 + 1]; }
    int stripe = (blockIdx.x + blockIdx.y * gridDim.x) & (STRIPES - 1);
    atomicAdd(&acc[accbase + stripe * 2], s);
    atomicAdd(&acc[accbase + stripe * 2 + 1], qd);
  }
}

__device__ __forceinline__ float block_inv_from_acc(
    const double* __restrict__ acc, int base, double n, float* sh)
{
  __syncthreads();
  int t = threadIdx.x;
  if (t < 64) {
    double s = acc[base + 2 * t], q = acc[base + 2 * t + 1];
    for (int off = 32; off; off >>= 1) {
      s += __shfl_down(s, off, 64);
      q += __shfl_down(q, off, 64);
    }
    if (t == 0) {
      double var = (q - s * s / n) / (n - 1.0);
      *sh = var > 0.0 ? (float)(0.5 / var) : __builtin_inff();
    }
  }
  __syncthreads();
  return *sh;
}

// exp -> crelu(cb1) -> [0.81,0.9,1]/3 pool -> hi/lo (Kp=256) + xn   (dist2 = d^2)
__global__ __launch_bounds__(256) void l2_sfm(
    const float* __restrict__ dist2, const double* __restrict__ acc, double n,
    const float* __restrict__ cb, u16* __restrict__ Xhi, u16* __restrict__ Xlo,
    float* __restrict__ xn, int c0, int sdistc, int sXc, int sxnc)
{
  __shared__ float shinv;
  __shared__ float red[4];
  int zi = blockIdx.z, c = c0 + zi;
  dist2 += (size_t)zi * sdistc;
  Xhi += (size_t)zi * sXc; Xlo += (size_t)zi * sXc; xn += (size_t)zi * sxnc;
  float inv = block_inv_from_acc(acc + (size_t)c * ACC_TOTAL, ACC_L2, n, &shinv);
  int b = blockIdx.x, u = blockIdx.y, ch = threadIdx.x;
  float bias = cb[1];
  float v = 0.f;
  if (ch < 225) {
    const float av[3] = {0.81f, 0.9f, 1.0f};
    float a = 0.f;
#pragma unroll
    for (int vv = 0; vv < 3; ++vv) {
      float d2 = dist2[((size_t)b * 9 + u * 3 + vv) * 225 + ch];
      float e = fexp(-d2 * inv);
      e = (e >= bias) ? e : 0.f;
      a = fmaf(e, av[vv], a);
    }
    v = a * (1.f / 3.f);
  }
  size_t row = (size_t)b * 3 + u;
  u16 h = f2bf(v);
  u16 l = f2bf(v - bf2f(h));
  Xhi[row * 256 + ch] = h;
  Xlo[row * 256 + ch] = l;
  float p = v * v;
  for (int off = 32; off; off >>= 1) p += __shfl_down(p, off, 64);
  if ((ch & 63) == 0) red[ch >> 6] = p;
  __syncthreads();
  if (ch == 0) xn[row] = red[0] + red[1] + red[2] + red[3];
}

// exp -> crelu(cb2) -> [0.81,0.9,1]/3 pool -> hi/lo (Kp=640) + xn   (dist3 = d^2)
__global__ __launch_bounds__(256) void l3_sfm(
    const float* __restrict__ dist3, const double* __restrict__ acc, double n,
    const float* __restrict__ cb, u16* __restrict__ Xhi, u16* __restrict__ Xlo,
    float* __restrict__ xn, int c0, int sdistc, int sXc, int sxnc)
{
  __shared__ float shinv;
  __shared__ float red[4];
  int zi = blockIdx.y, c = c0 + zi;
  dist3 += (size_t)zi * sdistc;
  Xhi += (size_t)zi * sXc; Xlo += (size_t)zi * sXc; xn += (size_t)zi * sxnc;
  float inv = block_inv_from_acc(acc + (size_t)c * ACC_TOTAL, ACC_L3, n, &shinv);
  int b = blockIdx.x, t = threadIdx.x;
  float bias = cb[2];
  const float au[3] = {0.81f, 0.9f, 1.0f};
  float p = 0.f;
  for (int ch = t; ch < 640; ch += 256) {
    float v = 0.f;
    if (ch < 625) {
      float a = 0.f;
#pragma unroll
      for (int u = 0; u < 3; ++u) {
        float d2 = dist3[((size_t)b * 3 + u) * 625 + ch];
        float e = fexp(-d2 * inv);
        e = (e >= bias) ? e : 0.f;
        a = fmaf(e, au[u], a);
      }
      v = a * (1.f / 3.f);
    }
    u16 h = f2bf(v);
    u16 l = f2bf(v - bf2f(h));
    Xhi[(size_t)b * 640 + ch] = h;
    Xlo[(size_t)b * 640 + ch] = l;
    p = fmaf(v, v, p);
  }
  for (int off = 32; off; off >>= 1) p += __shfl_down(p, off, 64);
  if ((t & 63) == 0) red[t >> 6] = p;
  __syncthreads();
  if (t == 0) xn[b] = red[0] + red[1] + red[2] + red[3];
}

// L4 exp/crelu fused into FC; loops nc channels internally  (dist4 = d^2)
__global__ __launch_bounds__(128) void fc_acc(
    const float* __restrict__ dist4, const double* __restrict__ acc, double n,
    const float* __restrict__ cb, const float* __restrict__ fcw,
    const float* __restrict__ fcb, float* __restrict__ out,
    int c0, int nc, int sdistc)
{
  __shared__ float shinv;
  int b = blockIdx.x, t = threadIdx.x;
  float bias = cb[3];
  float p[10];
#pragma unroll
  for (int k = 0; k < 10; ++k) p[k] = 0.f;
  for (int zi = 0; zi < nc; ++zi) {
    int c = c0 + zi;
    float inv = block_inv_from_acc(acc + (size_t)c * ACC_TOTAL, ACC_L4, n, &shinv);
    const float* d4 = dist4 + (size_t)zi * sdistc;
    for (int j = t; j < 1225; j += 128) {
      float d2 = d4[(size_t)b * 1225 + j];
      float v = fexp(-d2 * inv);
      v = (v >= bias) ? v : 0.f;
#pragma unroll
      for (int k = 0; k < 10; ++k) p[k] = fmaf(v, fcw[k * 3675 + c * 1225 + j], p[k]);
    }
  }
#pragma unroll
  for (int k = 0; k < 10; ++k)
    for (int off = 32; off; off >>= 1) p[k] += __shfl_down(p[k], off, 64);
  __shared__ float red[2][10];
  int wave = t >> 6;
  if ((t & 63) == 0) {
#pragma unroll
    for (int k = 0; k < 10; ++k) red[wave][k] = p[k];
  }
  __syncthreads();
  if (t < 10) {
    float v = red[0][t] + red[1][t];
    if (c0 == 0) out[(size_t)b * 10 + t] = fcb[t] + v;
    else         out[(size_t)b * 10 + t] += v;
  }
}

extern "C" void kernel_launch(void* const* d_in, const int* in_sizes, int n_in,
                              void* d_out, int out_size, void* d_ws, size_t ws_size,
                              hipStream_t stream) {
  const float* x   = (const float*)d_in[0];
  const float* w1  = (const float*)d_in[1];
  const float* w2  = (const float*)d_in[2];
  const float* w3  = (const float*)d_in[3];
  const float* w4  = (const float*)d_in[4];
  const float* fcw = (const float*)d_in[5];
  const float* fcb = (const float*)d_in[6];
  const float* cb  = (const float*)d_in[7];
  float* out = (float*)d_out;
  const int B = in_sizes[0] / (3 * 28 * 28);   // 4096
  const int M2 = B * 9, M3 = B * 3;
  const int NB = B / 2;

  const size_t W2SZ = 256 * 128, W3SZ = 768 * 256, W4SZ = (size_t)1280 * 640;
  const size_t WTOT = 3 * (W2SZ + W3SZ + W4SZ);

  // tier 0: L1 batched (d1 x3) + L2-4 batched; tier 1: L1 serial, L2-4 batched;
  // tier 2: everything channel-serial.
  int tier;
  u16 *Xbase, *Whi, *Wlo, *W1h, *W1l;
  float *wn, *w1n, *xn, *inv36, *part;
  double* accd;
  float* Sf;
  for (tier = 0; tier < 3; ++tier) {
    size_t cur = 0;
    char* basep = (char*)d_ws;
    auto take = [&](size_t bytes) {
      void* r = basep + cur;
      cur = (cur + bytes + 255) & ~(size_t)255;
      return r;
    };
    int nc = (tier <= 1) ? 3 : 1;
    int ncL1 = (tier == 0) ? 3 : 1;
    size_t Ssz = (size_t)M2 * 225 * 4 * nc;
    size_t d1sz = (size_t)B * 3600 * 4 * ncL1;
    if (d1sz > Ssz) Ssz = d1sz;
    Sf = (float*)take(Ssz);
    Xbase = (u16*)take((size_t)M2 * 128 * 2 * 2 * nc);
    Whi = (u16*)take(WTOT * 2); Wlo = (u16*)take(WTOT * 2);
    W1h = (u16*)take(12288 * 2); W1l = (u16*)take(12288 * 2);
    wn  = (float*)take(3 * (256 + 768 + 1280) * 4);
    w1n = (float*)take(384 * 4);
    xn    = (float*)take((size_t)M2 * 4 * nc);
    inv36 = (float*)take(40 * 4 * ncL1);
    part  = (float*)take((size_t)72 * STRIPES * 4 * ncL1);
    accd  = (double*)take(3 * ACC_TOTAL * 8);
    if (cur <= ws_size || tier == 2) break;
  }
  const int nc = (tier <= 1) ? 3 : 1;
  const bool batL1 = (tier == 0);

  const int sX2c   = (nc == 3) ? M2 * 128 * 2 : 0;
  const int sX3c   = (nc == 3) ? M3 * 256 * 2 : 0;
  const int sX4c   = (nc == 3) ? B * 640 * 2 : 0;
  const int sD2c   = (nc == 3) ? M2 * 225 : 0;
  const int sD3c   = (nc == 3) ? M3 * 625 : 0;
  const int sD4c   = (nc == 3) ? B * 1225 : 0;
  const int sXn2c  = (nc == 3) ? M2 : 0;
  const int sXn3c  = (nc == 3) ? M3 : 0;
  const int sXn4c  = (nc == 3) ? B : 0;
  const int sD1c   = batL1 ? B * 3600 : 0;
  const int sPartc = batL1 ? 72 * STRIPES : 0;
  const int sInvL1 = batL1 ? 40 : 0;

  u16* x2hi = Xbase;   u16* x2lo = Xbase + (size_t)M2 * 128;
  u16* x3hi = Xbase;   u16* x3lo = Xbase + (size_t)M3 * 256;
  u16* x4hi = Xbase;   u16* x4lo = Xbase + (size_t)B * 640;
  u16* Whi2 = Whi;                 u16* Wlo2 = Wlo;                 float* wn2 = wn;
  u16* Whi3 = Whi + 3 * W2SZ;      u16* Wlo3 = Wlo + 3 * W2SZ;      float* wn3 = wn + 3 * 256;
  u16* Whi4 = Whi + 3 * (W2SZ + W3SZ); u16* Wlo4 = Wlo + 3 * (W2SZ + W3SZ);
  float* wn4 = wn + 3 * (256 + 768);

  zero_acc_kernel<<<(3 * ACC_TOTAL + 255) / 256, 256, 0, stream>>>(accd, 3 * ACC_TOTAL);
  w_prep<<<dim3(128, 3),  128, 0, stream>>>(w1, 100, 25,  128, 32,  W1h,  W1l,  w1n);
  w_prep<<<dim3(256, 3),  128, 0, stream>>>(w2, 225, 100, 256, 128, Whi2, Wlo2, wn2);
  w_prep<<<dim3(768, 3),  128, 0, stream>>>(w3, 625, 225, 768, 256, Whi3, Wlo3, wn3);
  w_prep<<<dim3(1280, 3), 128, 0, stream>>>(w4, 1225, 625, 1280, 640, Whi4, Wlo4, wn4);

  for (int c0 = 0; c0 < 3; c0 += nc) {
    // ---- L1 ----
    if (batL1) {
      l1_gemm_d2<<<dim3(NB, 3), 256, 0, stream>>>(x, 0, W1h, W1l, w1n, Sf, sD1c);
      l1_reduce_bw<<<dim3(36, STRIPES, 3), 256, 0, stream>>>(Sf, sD1c, B, part, sPartc);
      l1_part_fin<<<dim3(36, 3), 256, 0, stream>>>(part, sPartc, inv36, sInvL1,
                                                   (double)B * 100.0);
      l1_sfm_lite<<<dim3(B, 3), 128, 0, stream>>>(
          Sf, sD1c, inv36, sInvL1, cb, x2hi, x2lo, xn, sX2c, sXn2c);
    } else {
      for (int ci = 0; ci < nc; ++ci) {
        int c = c0 + ci;
        l1_gemm_d2<<<dim3(NB, 1), 256, 0, stream>>>(x, c, W1h, W1l, w1n, Sf, 0);
        l1_reduce_bw<<<dim3(36, STRIPES, 1), 256, 0, stream>>>(Sf, 0, B, part, 0);
        l1_part_fin<<<dim3(36, 1), 256, 0, stream>>>(part, 0, inv36, 0,
                                                     (double)B * 100.0);
        l1_sfm_lite<<<dim3(B, 1), 128, 0, stream>>>(
            Sf, 0, inv36, 0, cb, x2hi + (size_t)ci * sX2c, x2lo + (size_t)ci * sX2c,
            xn + (size_t)ci * sXn2c, 0, 0);
      }
    }

    // L2: (M2 x 128) x (256 x 128) -> dist2 (M2 x 225)
    gemm_dist_pipe<<<dim3(M2 / 256, 1, nc), 512, 0, stream>>>(
        x2hi, x2lo, Whi2, Wlo2, xn, wn2, Sf, 225, 128, accd, ACC_L2, c0,
        sX2c, (int)W2SZ, sXn2c, 256, sD2c);
    l2_sfm<<<dim3(B, 3, nc), 256, 0, stream>>>(
        Sf, accd, (double)M2 * 225.0, cb, x3hi, x3lo, xn, c0, sD2c, sX3c, sXn3c);

    // L3: (M3 x 256) x (768 x 256) -> dist3 (M3 x 625)
    gemm_dist_pipe<<<dim3(M3 / 256, 3, nc), 512, 0, stream>>>(
        x3hi, x3lo, Whi3, Wlo3, xn, wn3, Sf, 625, 256, accd, ACC_L3, c0,
        sX3c, (int)W3SZ, sXn3c, 768, sD3c);
    l3_sfm<<<dim3(B, nc), 256, 0, stream>>>(
        Sf, accd, (double)M3 * 625.0, cb, x4hi, x4lo, xn, c0, sD3c, sX4c, sXn4c);

    // L4: (B x 640) x (1280 x 640) -> dist4 (B x 1225)
    gemm_dist_pipe<<<dim3(B / 256, 5, nc), 512, 0, stream>>>(
        x4hi, x4lo, Whi4, Wlo4, xn, wn4, Sf, 1225, 640, accd, ACC_L4, c0,
        sX4c, (int)W4SZ, sXn4c, 1280, sD4c);
    fc_acc<<<B, 128, 0, stream>>>(
        Sf, accd, (double)B * 1225.0, cb, fcw, fcb, out, c0, nc, sD4c);
  }
}